// Round 1
// 1394.035 us; speedup vs baseline: 1.1021x; 1.1021x over previous
//
#include <hip/hip_runtime.h>
#include <hip/hip_bf16.h>
#include <math.h>

#define C 128
#define NN 50000
#define EE 600000
#define GG 256
#define PI_F 3.14159265358979323846f
#define EPS_BN 1e-5f

typedef __attribute__((ext_vector_type(8)))  short  short8;
typedef __attribute__((ext_vector_type(16))) float  floatx16;
typedef __attribute__((ext_vector_type(4)))  float  float4v;
typedef __attribute__((ext_vector_type(4)))  unsigned short ushort4v;

static __device__ __forceinline__ short f2bs(float x) {   // f32 -> bf16 bits (RNE)
    union { float f; unsigned u; } v; v.f = x;
    unsigned r = v.u + 0x7FFF + ((v.u >> 16) & 1);
    return (short)(r >> 16);
}
static __device__ __forceinline__ float bs2f(unsigned short b) {
    union { unsigned u; float f; } v; v.u = (unsigned)b << 16; return v.f;
}

// ---------------- f32 -> bf16 cast (vectorized) ----------------
__global__ void k_cast(const float* __restrict__ in, unsigned short* __restrict__ out, int n4) {
    int i = blockIdx.x * blockDim.x + threadIdx.x;
    if (i < n4) {
        float4v v = ((const float4v*)in)[i];
        ushort4v o;
        o.x = (unsigned short)f2bs(v.x); o.y = (unsigned short)f2bs(v.y);
        o.z = (unsigned short)f2bs(v.z); o.w = (unsigned short)f2bs(v.w);
        ((ushort4v*)out)[i] = o;
    }
}

// ---------------- CSR build ----------------
__global__ void k_count(const int* __restrict__ dst, int* __restrict__ deg) {
    int e = blockIdx.x * blockDim.x + threadIdx.x;
    if (e < EE) atomicAdd(&deg[dst[e]], 1);
}

__global__ void k_scan(const int* __restrict__ deg, int* __restrict__ row_ptr) {
    __shared__ int s[1024];
    int t = threadIdx.x;
    const int CH = (NN + 1023) / 1024;
    int base = t * CH;
    int loc = 0;
    for (int i = 0; i < CH; i++) { int idx = base + i; if (idx < NN) loc += deg[idx]; }
    s[t] = loc; __syncthreads();
    for (int off = 1; off < 1024; off <<= 1) {
        int v = (t >= off) ? s[t - off] : 0;
        __syncthreads();
        s[t] += v;
        __syncthreads();
    }
    int run = (t == 0) ? 0 : s[t - 1];
    for (int i = 0; i < CH; i++) {
        int idx = base + i;
        if (idx < NN) { row_ptr[idx] = run; run += deg[idx]; }
    }
    if (t == 0) row_ptr[NN] = s[1023];
}

// fill CSR: eid (edge id per slot, for the permuting cast) + scsr/dcsr (src/dst per slot)
__global__ void k_fill(const int* __restrict__ src, const int* __restrict__ dst,
                       const int* __restrict__ row_ptr, int* __restrict__ fill,
                       int* __restrict__ eid, int* __restrict__ scsr, int* __restrict__ dcsr) {
    int e = blockIdx.x * blockDim.x + threadIdx.x;
    if (e < EE) {
        int d = dst[e];
        int pos = atomicAdd(&fill[d], 1);
        int i = row_ptr[d] + pos;
        eid[i] = e;
        scsr[i] = src[e];
        dcsr[i] = d;
    }
}

// ---------------- permuting cast: ea_csr[i] = bf16(ea[eid[i]]), one wave per row ----
__global__ void k_cast_perm(const float* __restrict__ ea, const int* __restrict__ eid,
                            unsigned short* __restrict__ out) {
    int i = blockIdx.x * 4 + (threadIdx.x >> 6);
    int lane = threadIdx.x & 63;
    if (i >= EE) return;
    int e = eid[i];
    const float2* rp = (const float2*)(ea + (size_t)e * C);
    float2 v = rp[lane];
    unsigned pk = (unsigned)(unsigned short)f2bs(v.x) | ((unsigned)(unsigned short)f2bs(v.y) << 16);
    ((unsigned*)(out + (size_t)i * C))[lane] = pk;
}

// ---------------- esum[n] = mean of incoming ea rows (CSR order: streaming) --------
__global__ void k_esum(const unsigned short* __restrict__ ea_csr, const int* __restrict__ row_ptr,
                       unsigned short* __restrict__ esum) {
    int n = blockIdx.x; int c = threadIdx.x;
    int s = row_ptr[n], e = row_ptr[n + 1];
    float acc = 0.f;
    for (int i = s; i < e; i++) acc += bs2f(ea_csr[(size_t)i * C + c]);
    esum[(size_t)n * C + c] = (unsigned short)f2bs(acc / fmaxf((float)(e - s), 1.f));
}

// ---------------- MFMA GEMM (bf16 A): out = A @ W + b ----------------
template<bool TANH, bool OUT_BF16>
__launch_bounds__(256)
__global__ void k_gemm(const unsigned short* __restrict__ A, const float* __restrict__ W,
                       const float* __restrict__ bias, void* __restrict__ outv, int M) {
    __shared__ short sWT[C * 136];
    for (int i = threadIdx.x; i < C * C; i += 256) {
        int k = i >> 7, n = i & (C - 1);
        sWT[n * 136 + k] = f2bs(W[i]);
    }
    __syncthreads();

    int lane = threadIdx.x & 63;
    int wave = threadIdx.x >> 6;
    int m    = lane & 31;
    int half = lane >> 5;
    int row0 = blockIdx.x * 128 + wave * 32;
    int rowA = row0 + m;
    int rowC = (rowA < M) ? rowA : (M - 1);
    const unsigned short* rp = A + (size_t)rowC * C;

    floatx16 acc[4];
    #pragma unroll
    for (int t = 0; t < 4; ++t)
        #pragma unroll
        for (int r = 0; r < 16; ++r) acc[t][r] = 0.f;

    #pragma unroll
    for (int s = 0; s < 8; ++s) {
        int k0 = s * 16 + half * 8;
        short8 af = *(const short8*)(rp + k0);
        #pragma unroll
        for (int t = 0; t < 4; ++t) {
            short8 bfr = *(const short8*)(&sWT[(t * 32 + m) * 136 + k0]);
            acc[t] = __builtin_amdgcn_mfma_f32_32x32x16_bf16(af, bfr, acc[t], 0, 0, 0);
        }
    }

    #pragma unroll
    for (int t = 0; t < 4; ++t) {
        int n = t * 32 + m;
        float b = bias ? bias[n] : 0.f;
        #pragma unroll
        for (int r = 0; r < 16; ++r) {
            int rl  = (r & 3) + 8 * (r >> 2) + 4 * half;
            int row = row0 + rl;
            if (row < M) {
                float v = acc[t][r] + b;
                if (TANH) v = tanhf(v);
                if (OUT_BF16) ((unsigned short*)outv)[(size_t)row * C + n] = (unsigned short)f2bs(v);
                else          ((float*)outv)[(size_t)row * C + n] = v;
            }
        }
    }
}

// ---------------- dual GEMM: xl = A@W0+b0, xr = A@W1+b1 (A frags cached) --------
__launch_bounds__(256)
__global__ void k_gemm2(const unsigned short* __restrict__ A,
                        const float* __restrict__ W0, const float* __restrict__ b0,
                        const float* __restrict__ W1, const float* __restrict__ b1,
                        unsigned short* __restrict__ out0, unsigned short* __restrict__ out1,
                        int M) {
    __shared__ short sWT[C * 136];
    int lane = threadIdx.x & 63;
    int wave = threadIdx.x >> 6;
    int m    = lane & 31;
    int half = lane >> 5;
    int row0 = blockIdx.x * 128 + wave * 32;
    int rowA = row0 + m;
    int rowC = (rowA < M) ? rowA : (M - 1);
    const unsigned short* rp = A + (size_t)rowC * C;

    short8 af[8];
    #pragma unroll
    for (int s = 0; s < 8; ++s) af[s] = *(const short8*)(rp + s * 16 + half * 8);

    for (int phase = 0; phase < 2; ++phase) {
        const float* W = phase ? W1 : W0;
        const float* bb = phase ? b1 : b0;
        unsigned short* out = phase ? out1 : out0;
        if (phase) __syncthreads();   // all waves done reading previous sWT
        for (int i = threadIdx.x; i < C * C; i += 256) {
            int k = i >> 7, n = i & (C - 1);
            sWT[n * 136 + k] = f2bs(W[i]);
        }
        __syncthreads();

        floatx16 acc[4];
        #pragma unroll
        for (int t = 0; t < 4; ++t)
            #pragma unroll
            for (int r = 0; r < 16; ++r) acc[t][r] = 0.f;

        #pragma unroll
        for (int s = 0; s < 8; ++s) {
            int k0 = s * 16 + half * 8;
            #pragma unroll
            for (int t = 0; t < 4; ++t) {
                short8 bfr = *(const short8*)(&sWT[(t * 32 + m) * 136 + k0]);
                acc[t] = __builtin_amdgcn_mfma_f32_32x32x16_bf16(af[s], bfr, acc[t], 0, 0, 0);
            }
        }

        #pragma unroll
        for (int t = 0; t < 4; ++t) {
            int n = t * 32 + m;
            float b = bb[n];
            #pragma unroll
            for (int r = 0; r < 16; ++r) {
                int rl  = (r & 3) + 8 * (r >> 2) + 4 * half;
                int row = row0 + rl;
                if (row < M)
                    out[(size_t)row * C + n] = (unsigned short)f2bs(acc[t][r] + b);
            }
        }
    }
}

// ---------------- fused GEMM + attention logit (CSR order for edges) -----------
// SELF: row i is node i (si = di = i). !SELF: row i is CSR slot i, si = scsr[i], di = dcsr[i]
// (dcsr is sorted => xr gathers have strong locality; A rows and aout are streaming).
template<bool SELF>
__launch_bounds__(256)
__global__ void k_gemm_logit(const unsigned short* __restrict__ A, const float* __restrict__ W,
                             const unsigned short* __restrict__ xl, const unsigned short* __restrict__ xr,
                             const int* __restrict__ scsr, const int* __restrict__ dcsr,
                             const float* __restrict__ att, float* __restrict__ aout, int M) {
    __shared__ short sWT[C * 136];
    for (int i = threadIdx.x; i < C * C; i += 256) {
        int k = i >> 7, n = i & (C - 1);
        sWT[n * 136 + k] = f2bs(W[i]);
    }
    __syncthreads();

    int lane = threadIdx.x & 63;
    int wave = threadIdx.x >> 6;
    int m    = lane & 31;
    int half = lane >> 5;
    int row0 = blockIdx.x * 128 + wave * 32;
    int rowA = row0 + m;
    int rowC = (rowA < M) ? rowA : (M - 1);
    const unsigned short* rp = A + (size_t)rowC * C;

    floatx16 acc[4];
    #pragma unroll
    for (int t = 0; t < 4; ++t)
        #pragma unroll
        for (int r = 0; r < 16; ++r) acc[t][r] = 0.f;

    #pragma unroll
    for (int s = 0; s < 8; ++s) {
        int k0 = s * 16 + half * 8;
        short8 af = *(const short8*)(rp + k0);
        #pragma unroll
        for (int t = 0; t < 4; ++t) {
            short8 bfr = *(const short8*)(&sWT[(t * 32 + m) * 136 + k0]);
            acc[t] = __builtin_amdgcn_mfma_f32_32x32x16_bf16(af, bfr, acc[t], 0, 0, 0);
        }
    }

    float attv[4];
    #pragma unroll
    for (int t = 0; t < 4; ++t) attv[t] = att[t * 32 + m];

    #pragma unroll
    for (int r = 0; r < 16; ++r) {
        int rl  = (r & 3) + 8 * (r >> 2) + 4 * half;
        int row = row0 + rl;
        int rc  = (row < M) ? row : (M - 1);
        int si, di;
        if (SELF) { si = rc; di = rc; }
        else      { si = scsr[rc]; di = dcsr[rc]; }
        const unsigned short* xls = xl + (size_t)si * C;
        const unsigned short* xrs = xr + (size_t)di * C;
        float p = 0.f;
        #pragma unroll
        for (int t = 0; t < 4; ++t) {
            int col = t * 32 + m;
            float v = acc[t][r] + bs2f(xls[col]) + bs2f(xrs[col]);
            v = (v >= 0.f) ? v : 0.2f * v;
            p = fmaf(v, attv[t], p);
        }
        p += __shfl_xor(p, 1);  p += __shfl_xor(p, 2);  p += __shfl_xor(p, 4);
        p += __shfl_xor(p, 8);  p += __shfl_xor(p, 16);
        if (m == 0 && row < M) aout[row] = p;
    }
}

// ---------------- fused scatter-softmax + aggregation (wave per node) -----------
// CSR-order logits (sequential a reads), 4 edges in parallel per wave,
// 16B vectorized xl gathers (16 lanes x 8ch per edge slot).
__global__ void k_attn(const unsigned short* __restrict__ xl, const float* __restrict__ a,
                       const int* __restrict__ row_ptr, const int* __restrict__ scsr,
                       const float* __restrict__ bo, float* __restrict__ out) {
    int n = blockIdx.x * 4 + (threadIdx.x >> 6);
    int lane = threadIdx.x & 63;
    if (n >= NN) return;
    int s = row_ptr[n], e = row_ptr[n + 1];
    float aself = a[EE + n];
    float mx = aself;
    for (int i = s + lane; i < e; i += 64) mx = fmaxf(mx, a[i]);
    #pragma unroll
    for (int o = 1; o < 64; o <<= 1) mx = fmaxf(mx, __shfl_xor(mx, o));
    float part = (lane == 0) ? expf(aself - mx) : 0.f;
    for (int i = s + lane; i < e; i += 64) part += expf(a[i] - mx);
    #pragma unroll
    for (int o = 1; o < 64; o <<= 1) part += __shfl_xor(part, o);
    float inv = 1.f / part;

    int sub = lane >> 4;        // edge slot 0..3
    int cb  = (lane & 15) * 8;  // channel base, 8 channels per lane
    float acc[8];
    #pragma unroll
    for (int j = 0; j < 8; ++j) acc[j] = 0.f;

    if (sub == 0) {             // self-loop contribution (once)
        float w = expf(aself - mx) * inv;
        short8 v = *(const short8*)(xl + (size_t)n * C + cb);
        #pragma unroll
        for (int j = 0; j < 8; ++j) acc[j] = w * bs2f((unsigned short)v[j]);
    }

    for (int i = s + sub; i < e; i += 4) {
        float w = expf(a[i] - mx) * inv;
        int sd = scsr[i];
        short8 v = *(const short8*)(xl + (size_t)sd * C + cb);
        #pragma unroll
        for (int j = 0; j < 8; ++j) acc[j] = fmaf(w, bs2f((unsigned short)v[j]), acc[j]);
    }

    #pragma unroll
    for (int j = 0; j < 8; ++j) {
        acc[j] += __shfl_xor(acc[j], 16);
        acc[j] += __shfl_xor(acc[j], 32);
    }
    if (sub == 0) {
        float* op = out + (size_t)n * C + cb;
        float4v o0, o1;
        o0.x = acc[0] + bo[cb + 0]; o0.y = acc[1] + bo[cb + 1];
        o0.z = acc[2] + bo[cb + 2]; o0.w = acc[3] + bo[cb + 3];
        o1.x = acc[4] + bo[cb + 4]; o1.y = acc[5] + bo[cb + 5];
        o1.z = acc[6] + bo[cb + 6]; o1.w = acc[7] + bo[cb + 7];
        ((float4v*)op)[0] = o0;
        ((float4v*)op)[1] = o1;
    }
}

// ---------------- batchnorm ----------------
__global__ void k_bnstats(const float* __restrict__ v, float* __restrict__ sums) {
    int c = threadIdx.x;
    float s1 = 0.f, s2 = 0.f;
    for (int n = blockIdx.x; n < NN; n += gridDim.x) {
        float x = v[(size_t)n * C + c]; s1 += x; s2 += x * x;
    }
    atomicAdd(&sums[c], s1); atomicAdd(&sums[C + c], s2);
}

__global__ void k_bnapply(const float* __restrict__ v, const float* __restrict__ sums,
                          const float* __restrict__ g, const float* __restrict__ b,
                          unsigned short* __restrict__ h) {
    int idx = blockIdx.x * blockDim.x + threadIdx.x;
    if (idx >= NN * C) return;
    int c = idx & (C - 1);
    float mu  = sums[c] * (1.f / NN);
    float var = sums[C + c] * (1.f / NN) - mu * mu;
    float r = rsqrtf(var + EPS_BN);
    h[idx] = (unsigned short)f2bs(tanhf((v[idx] - mu) * r * g[c] + b[c]));
}

// ---------------- graph segment bounds ----------------
__global__ void k_bounds(const int* __restrict__ batch, int* __restrict__ gs, int* __restrict__ ge) {
    int n = blockIdx.x * blockDim.x + threadIdx.x;
    if (n >= NN) return;
    int b = batch[n];
    if (n == 0 || batch[n - 1] != b) gs[b] = n;
    if (n == NN - 1 || batch[n + 1] != b) ge[b] = n + 1;
}

// ---------------- attention pooling: online softmax, 2 rows in flight -----------
__global__ void k_pool(const unsigned short* __restrict__ gate, const unsigned short* __restrict__ h,
                       const int* __restrict__ gs, const int* __restrict__ ge,
                       float* __restrict__ pooled) {
    __shared__ float sm[C], sden[C], sacc[C];
    int g = blockIdx.x;
    int t = threadIdx.x;          // 256 threads
    int c = t & (C - 1);
    int half = t >> 7;            // row-parity group
    int s = gs[g], e = ge[g];
    float m = -1e30f, den = 0.f, acc = 0.f;
    for (int n = s + half; n < e; n += 2) {
        float gv = bs2f(gate[(size_t)n * C + c]);
        float hv = bs2f(h[(size_t)n * C + c]);
        float mn = fmaxf(m, gv);
        float sc = expf(m - mn);          // 0 on first iteration (m = -1e30)
        float w  = expf(gv - mn);
        den = den * sc + w;
        acc = acc * sc + w * hv;
        m = mn;
    }
    if (half) { sm[c] = m; sden[c] = den; sacc[c] = acc; }
    __syncthreads();
    if (!half) {
        float m2 = sm[c], den2 = sden[c], acc2 = sacc[c];
        float mn = fmaxf(m, m2);
        float a1 = expf(m - mn), a2 = expf(m2 - mn);
        float d  = den * a1 + den2 * a2;
        float ac = acc * a1 + acc2 * a2;
        pooled[g * C + c] = (e > s) ? ac / d : 0.f;
    }
}

// ---------------- final linear + tanh + split/scale ----------------
__global__ void k_final(const float* __restrict__ pooled, const float* __restrict__ Wf,
                        const float* __restrict__ bf, float* __restrict__ out) {
    __shared__ float row[C];
    int g = blockIdx.x; int j = threadIdx.x;
    row[j] = pooled[g * C + j];
    __syncthreads();
    float acc = bf[j];
    #pragma unroll 8
    for (int k = 0; k < C; k++) acc = fmaf(row[k], Wf[k * C + j], acc);
    float o = tanhf(acc);
    if (j < C / 2) out[g * (C / 2) + j] = o * PI_F;
    else out[GG * (C / 2) + g * (C / 2) + (j - C / 2)] = (o + 1.f) * PI_F;
}

extern "C" void kernel_launch(void* const* d_in, const int* in_sizes, int n_in,
                              void* d_out, int out_size, void* d_ws, size_t ws_size,
                              hipStream_t stream) {
    const float* x   = (const float*)d_in[0];
    const int*   ei  = (const int*)d_in[1];
    const float* ea  = (const float*)d_in[2];
    const int* batch = (const int*)d_in[3];
    const float *Wl1 = (const float*)d_in[4],  *bl1 = (const float*)d_in[5];
    const float *Wr1 = (const float*)d_in[6],  *br1 = (const float*)d_in[7];
    const float *We1 = (const float*)d_in[8],  *att1 = (const float*)d_in[9], *bo1 = (const float*)d_in[10];
    const float *Wl2 = (const float*)d_in[11], *bl2 = (const float*)d_in[12];
    const float *Wr2 = (const float*)d_in[13], *br2 = (const float*)d_in[14];
    const float *We2 = (const float*)d_in[15], *att2 = (const float*)d_in[16], *bo2 = (const float*)d_in[17];
    const float *g1  = (const float*)d_in[18], *be1 = (const float*)d_in[19];
    const float *g2  = (const float*)d_in[20], *be2 = (const float*)d_in[21];
    const float *Ag1 = (const float*)d_in[22], *bg1 = (const float*)d_in[23];
    const float *Ag2 = (const float*)d_in[24], *bg2 = (const float*)d_in[25];
    const float *Wf  = (const float*)d_in[26], *bf  = (const float*)d_in[27];
    const int* src = ei; const int* dst = ei + EE;

    char* wsb = (char*)d_ws;
    size_t off = 0;
    auto alloc = [&](size_t bytes) -> char* {
        char* p = wsb + off; off += (bytes + 255) & ~(size_t)255; return p;
    };
    unsigned short* ea_u  = (unsigned short*)alloc((size_t)EE * C * 2);   // CSR-ordered bf16 edge_attr
    unsigned short* x_u   = (unsigned short*)alloc((size_t)NN * C * 2);
    unsigned short* xl_u  = (unsigned short*)alloc((size_t)NN * C * 2);
    unsigned short* xr_u  = (unsigned short*)alloc((size_t)NN * C * 2);
    unsigned short* h_u   = (unsigned short*)alloc((size_t)NN * C * 2);
    unsigned short* es_u  = (unsigned short*)alloc((size_t)NN * C * 2);
    float* aggf  = (float*)alloc((size_t)NN * C * 4);
    float* a     = (float*)alloc((size_t)(EE + NN) * 4);  // CSR slots | self
    int*   csrz  = (int*)alloc((size_t)2 * NN * 4);       // deg | fill (zeroed together)
    int* deg = csrz, *fill = csrz + NN;
    int* row_ptr = (int*)alloc((size_t)(NN + 1) * 4);
    int* eid     = (int*)alloc((size_t)EE * 4);
    int* scsr    = (int*)alloc((size_t)EE * 4);
    int* dcsr    = (int*)alloc((size_t)EE * 4);
    float* sums  = (float*)alloc(4 * C * 4);              // layer1 | layer2
    int* gbounds = (int*)alloc(2 * GG * 4);
    int* gs = gbounds, *ge = gbounds + GG;
    float* pooled= (float*)alloc(GG * C * 4);

    hipMemsetAsync(csrz,    0, (size_t)2 * NN * 4, stream);
    hipMemsetAsync(sums,    0, 4 * C * 4, stream);
    hipMemsetAsync(gbounds, 0, 2 * GG * 4, stream);

    k_cast<<<(NN * C / 4 + 255) / 256, 256, 0, stream>>>(x, x_u, NN * C / 4);
    k_count<<<(EE + 255) / 256, 256, 0, stream>>>(dst, deg);
    k_scan<<<1, 1024, 0, stream>>>(deg, row_ptr);
    k_fill<<<(EE + 255) / 256, 256, 0, stream>>>(src, dst, row_ptr, fill, eid, scsr, dcsr);
    k_cast_perm<<<(EE + 3) / 4, 256, 0, stream>>>(ea, eid, ea_u);
    k_esum<<<NN, C, 0, stream>>>(ea_u, row_ptr, es_u);

    int gN = (NN + 127) / 128, gE = (EE + 127) / 128;

    // ---- layer 1 ----
    k_gemm2<<<gN, 256, 0, stream>>>(x_u, Wl1, bl1, Wr1, br1, xl_u, xr_u, NN);
    k_gemm_logit<true ><<<gN, 256, 0, stream>>>(es_u, We1, xl_u, xr_u, nullptr, nullptr, att1, a + EE, NN);
    k_gemm_logit<false><<<gE, 256, 0, stream>>>(ea_u, We1, xl_u, xr_u, scsr, dcsr, att1, a, EE);
    k_attn<<<(NN + 3) / 4, 256, 0, stream>>>(xl_u, a, row_ptr, scsr, bo1, aggf);
    k_bnstats<<<256, C, 0, stream>>>(aggf, sums);
    k_bnapply<<<(NN * C + 255) / 256, 256, 0, stream>>>(aggf, sums, g1, be1, h_u);

    // ---- layer 2 ----
    k_gemm2<<<gN, 256, 0, stream>>>(h_u, Wl2, bl2, Wr2, br2, xl_u, xr_u, NN);
    k_gemm_logit<true ><<<gN, 256, 0, stream>>>(es_u, We2, xl_u, xr_u, nullptr, nullptr, att2, a + EE, NN);
    k_gemm_logit<false><<<gE, 256, 0, stream>>>(ea_u, We2, xl_u, xr_u, scsr, dcsr, att2, a, EE);
    k_attn<<<(NN + 3) / 4, 256, 0, stream>>>(xl_u, a, row_ptr, scsr, bo2, aggf);
    k_bnstats<<<256, C, 0, stream>>>(aggf, sums + 2 * C);
    k_bnapply<<<(NN * C + 255) / 256, 256, 0, stream>>>(aggf, sums + 2 * C, g2, be2, h_u);

    // ---- pooling + head ----
    k_gemm<true,  true><<<gN, 256, 0, stream>>>(h_u,  Ag1, bg1, xl_u, NN);
    k_gemm<false, true><<<gN, 256, 0, stream>>>(xl_u, Ag2, bg2, xr_u, NN);
    k_bounds<<<(NN + 255) / 256, 256, 0, stream>>>(batch, gs, ge);
    k_pool<<<GG, 256, 0, stream>>>(xr_u, h_u, gs, ge, pooled);
    k_final<<<GG, C, 0, stream>>>(pooled, Wf, bf, (float*)d_out);
}

// Round 2
// 1131.498 us; speedup vs baseline: 1.3578x; 1.2320x over previous
//
#include <hip/hip_runtime.h>
#include <hip/hip_bf16.h>
#include <math.h>

#define C 128
#define NN 50000
#define EE 600000
#define GG 256
#define PI_F 3.14159265358979323846f
#define EPS_BN 1e-5f
#define SCAN_G ((NN + 255) / 256)   // 196 blocks

typedef __attribute__((ext_vector_type(8)))  short  short8;
typedef __attribute__((ext_vector_type(16))) float  floatx16;
typedef __attribute__((ext_vector_type(4)))  float  float4v;
typedef __attribute__((ext_vector_type(4)))  unsigned short ushort4v;

static __device__ __forceinline__ short f2bs(float x) {   // f32 -> bf16 bits (RNE)
    union { float f; unsigned u; } v; v.f = x;
    unsigned r = v.u + 0x7FFF + ((v.u >> 16) & 1);
    return (short)(r >> 16);
}
static __device__ __forceinline__ float bs2f(unsigned short b) {
    union { unsigned u; float f; } v; v.u = (unsigned)b << 16; return v.f;
}

// ---------------- f32 -> bf16 cast (vectorized) ----------------
__global__ void k_cast(const float* __restrict__ in, unsigned short* __restrict__ out, int n4) {
    int i = blockIdx.x * blockDim.x + threadIdx.x;
    if (i < n4) {
        float4v v = ((const float4v*)in)[i];
        ushort4v o;
        o.x = (unsigned short)f2bs(v.x); o.y = (unsigned short)f2bs(v.y);
        o.z = (unsigned short)f2bs(v.z); o.w = (unsigned short)f2bs(v.w);
        ((ushort4v*)out)[i] = o;
    }
}

// ---------------- weight prep: cast + transpose 8 matrices to bf16 [n][k] -------
__global__ void k_prep(const float* __restrict__ W0, const float* __restrict__ W1,
                       const float* __restrict__ W2, const float* __restrict__ W3,
                       const float* __restrict__ W4, const float* __restrict__ W5,
                       const float* __restrict__ W6, const float* __restrict__ W7,
                       unsigned short* __restrict__ WT) {
    __shared__ short s[C * 136];
    const float* W;
    switch (blockIdx.x) {
        case 0: W = W0; break; case 1: W = W1; break;
        case 2: W = W2; break; case 3: W = W3; break;
        case 4: W = W4; break; case 5: W = W5; break;
        case 6: W = W6; break; default: W = W7; break;
    }
    for (int i = threadIdx.x; i < C * C; i += 256) {
        int k = i >> 7, n = i & (C - 1);
        s[n * 136 + k] = f2bs(W[i]);           // coalesced global read, scattered LDS write
    }
    __syncthreads();
    unsigned short* out = WT + (size_t)blockIdx.x * C * C;
    for (int i8 = threadIdx.x; i8 < C * C / 8; i8 += 256) {
        int n = i8 >> 4, k0 = (i8 & 15) * 8;
        *(short8*)(out + n * C + k0) = *(const short8*)&s[n * 136 + k0];  // coalesced write
    }
}

// stage pre-transposed bf16 weights into padded LDS image (8 x short8 per thread)
static __device__ __forceinline__ void stage_wt(const unsigned short* __restrict__ WT, short* sWT) {
    for (int i8 = threadIdx.x; i8 < C * C / 8; i8 += 256) {
        int n = i8 >> 4, k0 = (i8 & 15) * 8;
        *(short8*)&sWT[n * 136 + k0] = *(const short8*)(WT + n * C + k0);
    }
}

// ---------------- CSR build ----------------
__global__ void k_count(const int* __restrict__ dst, int* __restrict__ deg) {
    int e = blockIdx.x * blockDim.x + threadIdx.x;
    if (e < EE) atomicAdd(&deg[dst[e]], 1);
}

__global__ void k_scan1(const int* __restrict__ deg, int* __restrict__ bsum) {
    __shared__ int s[256];
    int t = threadIdx.x;
    int idx = blockIdx.x * 256 + t;
    s[t] = (idx < NN) ? deg[idx] : 0;
    __syncthreads();
    for (int off = 128; off > 0; off >>= 1) {
        if (t < off) s[t] += s[t + off];
        __syncthreads();
    }
    if (t == 0) bsum[blockIdx.x] = s[0];
}

__global__ void k_scan2(const int* __restrict__ bsum, int* __restrict__ boff, int* __restrict__ row_ptr) {
    __shared__ int s[256];
    int t = threadIdx.x;
    int v0 = (t < SCAN_G) ? bsum[t] : 0;
    s[t] = v0;
    __syncthreads();
    for (int off = 1; off < 256; off <<= 1) {
        int v = (t >= off) ? s[t - off] : 0;
        __syncthreads();
        s[t] += v;
        __syncthreads();
    }
    if (t < SCAN_G) boff[t] = s[t] - v0;   // exclusive
    if (t == 255) row_ptr[NN] = s[255];
}

__global__ void k_scan3(const int* __restrict__ deg, const int* __restrict__ boff,
                        int* __restrict__ row_ptr) {
    __shared__ int s[256];
    int t = threadIdx.x;
    int idx = blockIdx.x * 256 + t;
    int v = (idx < NN) ? deg[idx] : 0;
    s[t] = v;
    __syncthreads();
    for (int off = 1; off < 256; off <<= 1) {
        int u = (t >= off) ? s[t - off] : 0;
        __syncthreads();
        s[t] += u;
        __syncthreads();
    }
    if (idx < NN) row_ptr[idx] = boff[blockIdx.x] + s[t] - v;   // exclusive
}

// fill CSR: eid (edge id per slot) + scsr/dcsr (src/dst per slot)
__global__ void k_fill(const int* __restrict__ src, const int* __restrict__ dst,
                       const int* __restrict__ row_ptr, int* __restrict__ fill,
                       int* __restrict__ eid, int* __restrict__ scsr, int* __restrict__ dcsr) {
    int e = blockIdx.x * blockDim.x + threadIdx.x;
    if (e < EE) {
        int d = dst[e];
        int pos = atomicAdd(&fill[d], 1);
        int i = row_ptr[d] + pos;
        eid[i] = e;
        scsr[i] = src[e];
        dcsr[i] = d;
    }
}

// ---------------- fused permuting cast + per-node mean (block per node) ---------
__global__ void k_cast_esum(const float* __restrict__ ea, const int* __restrict__ eid,
                            const int* __restrict__ row_ptr,
                            unsigned short* __restrict__ ea_csr, unsigned short* __restrict__ esum) {
    int n = blockIdx.x; int c = threadIdx.x;   // 128 threads
    int s = row_ptr[n], e = row_ptr[n + 1];
    float acc = 0.f;
    for (int i = s; i < e; i++) {
        float v = ea[(size_t)eid[i] * C + c];
        acc += v;
        ea_csr[(size_t)i * C + c] = (unsigned short)f2bs(v);
    }
    esum[(size_t)n * C + c] = (unsigned short)f2bs(acc / fmaxf((float)(e - s), 1.f));
}

// ---------------- MFMA GEMM (bf16 A): out = A @ W + b ----------------
template<bool TANH, bool OUT_BF16>
__launch_bounds__(256)
__global__ void k_gemm(const unsigned short* __restrict__ A, const unsigned short* __restrict__ WT,
                       const float* __restrict__ bias, void* __restrict__ outv, int M) {
    __shared__ short sWT[C * 136];
    stage_wt(WT, sWT);
    __syncthreads();

    int lane = threadIdx.x & 63;
    int wave = threadIdx.x >> 6;
    int m    = lane & 31;
    int half = lane >> 5;
    int row0 = blockIdx.x * 128 + wave * 32;
    int rowA = row0 + m;
    int rowC = (rowA < M) ? rowA : (M - 1);
    const unsigned short* rp = A + (size_t)rowC * C;

    floatx16 acc[4];
    #pragma unroll
    for (int t = 0; t < 4; ++t)
        #pragma unroll
        for (int r = 0; r < 16; ++r) acc[t][r] = 0.f;

    #pragma unroll
    for (int s = 0; s < 8; ++s) {
        int k0 = s * 16 + half * 8;
        short8 af = *(const short8*)(rp + k0);
        #pragma unroll
        for (int t = 0; t < 4; ++t) {
            short8 bfr = *(const short8*)(&sWT[(t * 32 + m) * 136 + k0]);
            acc[t] = __builtin_amdgcn_mfma_f32_32x32x16_bf16(af, bfr, acc[t], 0, 0, 0);
        }
    }

    #pragma unroll
    for (int t = 0; t < 4; ++t) {
        int n = t * 32 + m;
        float b = bias ? bias[n] : 0.f;
        #pragma unroll
        for (int r = 0; r < 16; ++r) {
            int rl  = (r & 3) + 8 * (r >> 2) + 4 * half;
            int row = row0 + rl;
            if (row < M) {
                float v = acc[t][r] + b;
                if (TANH) v = tanhf(v);
                if (OUT_BF16) ((unsigned short*)outv)[(size_t)row * C + n] = (unsigned short)f2bs(v);
                else          ((float*)outv)[(size_t)row * C + n] = v;
            }
        }
    }
}

// ---------------- dual GEMM: xl = A@W0+b0, xr = A@W1+b1 (A frags cached) --------
__launch_bounds__(256)
__global__ void k_gemm2(const unsigned short* __restrict__ A,
                        const unsigned short* __restrict__ WT0, const float* __restrict__ b0,
                        const unsigned short* __restrict__ WT1, const float* __restrict__ b1,
                        unsigned short* __restrict__ out0, unsigned short* __restrict__ out1,
                        int M) {
    __shared__ short sWT[C * 136];
    int lane = threadIdx.x & 63;
    int wave = threadIdx.x >> 6;
    int m    = lane & 31;
    int half = lane >> 5;
    int row0 = blockIdx.x * 128 + wave * 32;
    int rowA = row0 + m;
    int rowC = (rowA < M) ? rowA : (M - 1);
    const unsigned short* rp = A + (size_t)rowC * C;

    short8 af[8];
    #pragma unroll
    for (int s = 0; s < 8; ++s) af[s] = *(const short8*)(rp + s * 16 + half * 8);

    for (int phase = 0; phase < 2; ++phase) {
        const unsigned short* WT = phase ? WT1 : WT0;
        const float* bb = phase ? b1 : b0;
        unsigned short* out = phase ? out1 : out0;
        if (phase) __syncthreads();   // all waves done reading previous sWT
        stage_wt(WT, sWT);
        __syncthreads();

        floatx16 acc[4];
        #pragma unroll
        for (int t = 0; t < 4; ++t)
            #pragma unroll
            for (int r = 0; r < 16; ++r) acc[t][r] = 0.f;

        #pragma unroll
        for (int s = 0; s < 8; ++s) {
            int k0 = s * 16 + half * 8;
            #pragma unroll
            for (int t = 0; t < 4; ++t) {
                short8 bfr = *(const short8*)(&sWT[(t * 32 + m) * 136 + k0]);
                acc[t] = __builtin_amdgcn_mfma_f32_32x32x16_bf16(af[s], bfr, acc[t], 0, 0, 0);
            }
        }

        #pragma unroll
        for (int t = 0; t < 4; ++t) {
            int n = t * 32 + m;
            float b = bb[n];
            #pragma unroll
            for (int r = 0; r < 16; ++r) {
                int rl  = (r & 3) + 8 * (r >> 2) + 4 * half;
                int row = row0 + rl;
                if (row < M)
                    out[(size_t)row * C + n] = (unsigned short)f2bs(acc[t][r] + b);
            }
        }
    }
}

// ---------------- fused GEMM + attention logit (CSR order for edges) -----------
template<bool SELF>
__launch_bounds__(256)
__global__ void k_gemm_logit(const unsigned short* __restrict__ A, const unsigned short* __restrict__ WT,
                             const unsigned short* __restrict__ xl, const unsigned short* __restrict__ xr,
                             const int* __restrict__ scsr, const int* __restrict__ dcsr,
                             const float* __restrict__ att, float* __restrict__ aout, int M) {
    __shared__ short sWT[C * 136];
    stage_wt(WT, sWT);
    __syncthreads();

    int lane = threadIdx.x & 63;
    int wave = threadIdx.x >> 6;
    int m    = lane & 31;
    int half = lane >> 5;
    int row0 = blockIdx.x * 128 + wave * 32;
    int rowA = row0 + m;
    int rowC = (rowA < M) ? rowA : (M - 1);
    const unsigned short* rp = A + (size_t)rowC * C;

    floatx16 acc[4];
    #pragma unroll
    for (int t = 0; t < 4; ++t)
        #pragma unroll
        for (int r = 0; r < 16; ++r) acc[t][r] = 0.f;

    #pragma unroll
    for (int s = 0; s < 8; ++s) {
        int k0 = s * 16 + half * 8;
        short8 af = *(const short8*)(rp + k0);
        #pragma unroll
        for (int t = 0; t < 4; ++t) {
            short8 bfr = *(const short8*)(&sWT[(t * 32 + m) * 136 + k0]);
            acc[t] = __builtin_amdgcn_mfma_f32_32x32x16_bf16(af, bfr, acc[t], 0, 0, 0);
        }
    }

    float attv[4];
    #pragma unroll
    for (int t = 0; t < 4; ++t) attv[t] = att[t * 32 + m];

    #pragma unroll
    for (int r = 0; r < 16; ++r) {
        int rl  = (r & 3) + 8 * (r >> 2) + 4 * half;
        int row = row0 + rl;
        int rc  = (row < M) ? row : (M - 1);
        int si, di;
        if (SELF) { si = rc; di = rc; }
        else      { si = scsr[rc]; di = dcsr[rc]; }
        const unsigned short* xls = xl + (size_t)si * C;
        const unsigned short* xrs = xr + (size_t)di * C;
        float p = 0.f;
        #pragma unroll
        for (int t = 0; t < 4; ++t) {
            int col = t * 32 + m;
            float v = acc[t][r] + bs2f(xls[col]) + bs2f(xrs[col]);
            v = (v >= 0.f) ? v : 0.2f * v;
            p = fmaf(v, attv[t], p);
        }
        p += __shfl_xor(p, 1);  p += __shfl_xor(p, 2);  p += __shfl_xor(p, 4);
        p += __shfl_xor(p, 8);  p += __shfl_xor(p, 16);
        if (m == 0 && row < M) aout[row] = p;
    }
}

// ---------------- fused scatter-softmax + aggregation (wave per node) -----------
__global__ void k_attn(const unsigned short* __restrict__ xl, const float* __restrict__ a,
                       const int* __restrict__ row_ptr, const int* __restrict__ scsr,
                       const float* __restrict__ bo, float* __restrict__ out) {
    int n = blockIdx.x * 4 + (threadIdx.x >> 6);
    int lane = threadIdx.x & 63;
    if (n >= NN) return;
    int s = row_ptr[n], e = row_ptr[n + 1];
    float aself = a[EE + n];
    float mx = aself;
    for (int i = s + lane; i < e; i += 64) mx = fmaxf(mx, a[i]);
    #pragma unroll
    for (int o = 1; o < 64; o <<= 1) mx = fmaxf(mx, __shfl_xor(mx, o));
    float part = (lane == 0) ? expf(aself - mx) : 0.f;
    for (int i = s + lane; i < e; i += 64) part += expf(a[i] - mx);
    #pragma unroll
    for (int o = 1; o < 64; o <<= 1) part += __shfl_xor(part, o);
    float inv = 1.f / part;

    int sub = lane >> 4;        // edge slot 0..3
    int cb  = (lane & 15) * 8;  // channel base, 8 channels per lane
    float acc[8];
    #pragma unroll
    for (int j = 0; j < 8; ++j) acc[j] = 0.f;

    if (sub == 0) {             // self-loop contribution (once)
        float w = expf(aself - mx) * inv;
        short8 v = *(const short8*)(xl + (size_t)n * C + cb);
        #pragma unroll
        for (int j = 0; j < 8; ++j) acc[j] = w * bs2f((unsigned short)v[j]);
    }

    for (int i = s + sub; i < e; i += 4) {
        float w = expf(a[i] - mx) * inv;
        int sd = scsr[i];
        short8 v = *(const short8*)(xl + (size_t)sd * C + cb);
        #pragma unroll
        for (int j = 0; j < 8; ++j) acc[j] = fmaf(w, bs2f((unsigned short)v[j]), acc[j]);
    }

    #pragma unroll
    for (int j = 0; j < 8; ++j) {
        acc[j] += __shfl_xor(acc[j], 16);
        acc[j] += __shfl_xor(acc[j], 32);
    }
    if (sub == 0) {
        float* op = out + (size_t)n * C + cb;
        float4v o0, o1;
        o0.x = acc[0] + bo[cb + 0]; o0.y = acc[1] + bo[cb + 1];
        o0.z = acc[2] + bo[cb + 2]; o0.w = acc[3] + bo[cb + 3];
        o1.x = acc[4] + bo[cb + 4]; o1.y = acc[5] + bo[cb + 5];
        o1.z = acc[6] + bo[cb + 6]; o1.w = acc[7] + bo[cb + 7];
        ((float4v*)op)[0] = o0;
        ((float4v*)op)[1] = o1;
    }
}

// ---------------- batchnorm stats: 1024 threads, 8 rows in flight ---------------
__launch_bounds__(1024)
__global__ void k_bnstats(const float* __restrict__ v, float* __restrict__ sums) {
    __shared__ float r1[8][C], r2[8][C];
    int c = threadIdx.x & (C - 1);
    int q = threadIdx.x >> 7;   // 0..7
    float s1 = 0.f, s2 = 0.f;
    for (int n = blockIdx.x * 8 + q; n < NN; n += 8 * gridDim.x) {
        float x = v[(size_t)n * C + c]; s1 += x; s2 += x * x;
    }
    r1[q][c] = s1; r2[q][c] = s2;
    __syncthreads();
    if (threadIdx.x < C) {
        float a1 = 0.f, a2 = 0.f;
        #pragma unroll
        for (int k = 0; k < 8; ++k) { a1 += r1[k][c]; a2 += r2[k][c]; }
        atomicAdd(&sums[c], a1); atomicAdd(&sums[C + c], a2);
    }
}

__global__ void k_bnapply(const float* __restrict__ v, const float* __restrict__ sums,
                          const float* __restrict__ g, const float* __restrict__ b,
                          unsigned short* __restrict__ h) {
    int i4 = blockIdx.x * blockDim.x + threadIdx.x;
    if (i4 >= NN * C / 4) return;
    int c0 = (i4 * 4) & (C - 1);
    float4v x = ((const float4v*)v)[i4];
    ushort4v o;
    #pragma unroll
    for (int j = 0; j < 4; ++j) {
        int c = c0 + j;
        float mu  = sums[c] * (1.f / NN);
        float var = sums[C + c] * (1.f / NN) - mu * mu;
        float r = rsqrtf(var + EPS_BN);
        o[j] = (unsigned short)f2bs(tanhf((x[j] - mu) * r * g[c] + b[c]));
    }
    ((ushort4v*)h)[i4] = o;
}

// ---------------- graph segment bounds ----------------
__global__ void k_bounds(const int* __restrict__ batch, int* __restrict__ gs, int* __restrict__ ge) {
    int n = blockIdx.x * blockDim.x + threadIdx.x;
    if (n >= NN) return;
    int b = batch[n];
    if (n == 0 || batch[n - 1] != b) gs[b] = n;
    if (n == NN - 1 || batch[n + 1] != b) ge[b] = n + 1;
}

// ---------------- fused attention pooling + final linear (block per graph) ------
__launch_bounds__(1024)
__global__ void k_poolfinal(const unsigned short* __restrict__ gate, const unsigned short* __restrict__ h,
                            const int* __restrict__ gs, const int* __restrict__ ge,
                            const float* __restrict__ Wf, const float* __restrict__ bf,
                            float* __restrict__ out) {
    __shared__ float sm[8][C], sden[8][C], sacc[8][C];
    __shared__ float row[C];
    int g = blockIdx.x;
    int t = threadIdx.x;
    int c = t & (C - 1);
    int q = t >> 7;             // 0..7
    int s = gs[g], e = ge[g];
    float m = -1e30f, den = 0.f, acc = 0.f;
    for (int n = s + q; n < e; n += 8) {
        float gv = bs2f(gate[(size_t)n * C + c]);
        float hv = bs2f(h[(size_t)n * C + c]);
        float mn = fmaxf(m, gv);
        float sc = expf(m - mn);          // 0 on first iteration
        float w  = expf(gv - mn);
        den = den * sc + w;
        acc = acc * sc + w * hv;
        m = mn;
    }
    sm[q][c] = m; sden[q][c] = den; sacc[q][c] = acc;
    __syncthreads();
    if (t < C) {
        float M = sm[0][c];
        #pragma unroll
        for (int k = 1; k < 8; ++k) M = fmaxf(M, sm[k][c]);
        float D = 0.f, A = 0.f;
        #pragma unroll
        for (int k = 0; k < 8; ++k) {
            float al = expf(sm[k][c] - M);
            D += sden[k][c] * al;
            A += sacc[k][c] * al;
        }
        row[c] = (e > s) ? A / D : 0.f;
    }
    __syncthreads();
    // split-k GEMV: j = c, k-chunk per q
    float p = 0.f;
    #pragma unroll
    for (int kk = 0; kk < 16; ++kk) {
        int k = q * 16 + kk;
        p = fmaf(row[k], Wf[k * C + c], p);
    }
    sden[q][c] = p;             // reuse LDS for partials
    __syncthreads();
    if (t < C) {
        float accf = bf[c];
        #pragma unroll
        for (int k = 0; k < 8; ++k) accf += sden[k][c];
        float o = tanhf(accf);
        if (c < C / 2) out[g * (C / 2) + c] = o * PI_F;
        else out[GG * (C / 2) + g * (C / 2) + (c - C / 2)] = (o + 1.f) * PI_F;
    }
}

extern "C" void kernel_launch(void* const* d_in, const int* in_sizes, int n_in,
                              void* d_out, int out_size, void* d_ws, size_t ws_size,
                              hipStream_t stream) {
    const float* x   = (const float*)d_in[0];
    const int*   ei  = (const int*)d_in[1];
    const float* ea  = (const float*)d_in[2];
    const int* batch = (const int*)d_in[3];
    const float *Wl1 = (const float*)d_in[4],  *bl1 = (const float*)d_in[5];
    const float *Wr1 = (const float*)d_in[6],  *br1 = (const float*)d_in[7];
    const float *We1 = (const float*)d_in[8],  *att1 = (const float*)d_in[9], *bo1 = (const float*)d_in[10];
    const float *Wl2 = (const float*)d_in[11], *bl2 = (const float*)d_in[12];
    const float *Wr2 = (const float*)d_in[13], *br2 = (const float*)d_in[14];
    const float *We2 = (const float*)d_in[15], *att2 = (const float*)d_in[16], *bo2 = (const float*)d_in[17];
    const float *g1  = (const float*)d_in[18], *be1 = (const float*)d_in[19];
    const float *g2  = (const float*)d_in[20], *be2 = (const float*)d_in[21];
    const float *Ag1 = (const float*)d_in[22], *bg1 = (const float*)d_in[23];
    const float *Ag2 = (const float*)d_in[24], *bg2 = (const float*)d_in[25];
    const float *Wf  = (const float*)d_in[26], *bf  = (const float*)d_in[27];
    const int* src = ei; const int* dst = ei + EE;

    char* wsb = (char*)d_ws;
    size_t off = 0;
    auto alloc = [&](size_t bytes) -> char* {
        char* p = wsb + off; off += (bytes + 255) & ~(size_t)255; return p;
    };
    unsigned short* ea_u  = (unsigned short*)alloc((size_t)EE * C * 2);   // CSR-ordered bf16 edge_attr
    unsigned short* x_u   = (unsigned short*)alloc((size_t)NN * C * 2);
    unsigned short* xl_u  = (unsigned short*)alloc((size_t)NN * C * 2);
    unsigned short* xr_u  = (unsigned short*)alloc((size_t)NN * C * 2);
    unsigned short* h_u   = (unsigned short*)alloc((size_t)NN * C * 2);
    unsigned short* es_u  = (unsigned short*)alloc((size_t)NN * C * 2);
    unsigned short* WTall = (unsigned short*)alloc((size_t)8 * C * C * 2); // pre-transposed bf16 weights
    float* aggf  = (float*)alloc((size_t)NN * C * 4);
    float* a     = (float*)alloc((size_t)(EE + NN) * 4);  // CSR slots | self
    int*   csrz  = (int*)alloc((size_t)2 * NN * 4);       // deg | fill (zeroed together)
    int* deg = csrz, *fill = csrz + NN;
    int* row_ptr = (int*)alloc((size_t)(NN + 1) * 4);
    int* eid     = (int*)alloc((size_t)EE * 4);
    int* scsr    = (int*)alloc((size_t)EE * 4);
    int* dcsr    = (int*)alloc((size_t)EE * 4);
    float* sums  = (float*)alloc(4 * C * 4);              // layer1 | layer2
    int* gbounds = (int*)alloc(2 * GG * 4);
    int* gs = gbounds, *ge = gbounds + GG;
    int* bscan   = (int*)alloc((size_t)2 * SCAN_G * 4);
    int* bsum = bscan, *boff = bscan + SCAN_G;

    hipMemsetAsync(csrz,    0, (size_t)2 * NN * 4, stream);
    hipMemsetAsync(sums,    0, 4 * C * 4, stream);
    hipMemsetAsync(gbounds, 0, 2 * GG * 4, stream);

    const size_t WSZ = (size_t)C * C;
    const unsigned short *WTl1 = WTall + 0 * WSZ, *WTr1 = WTall + 1 * WSZ, *WTe1 = WTall + 2 * WSZ;
    const unsigned short *WTl2 = WTall + 3 * WSZ, *WTr2 = WTall + 4 * WSZ, *WTe2 = WTall + 5 * WSZ;
    const unsigned short *WTA1 = WTall + 6 * WSZ, *WTA2 = WTall + 7 * WSZ;

    k_prep<<<8, 256, 0, stream>>>(Wl1, Wr1, We1, Wl2, Wr2, We2, Ag1, Ag2, WTall);
    k_cast<<<(NN * C / 4 + 255) / 256, 256, 0, stream>>>(x, x_u, NN * C / 4);
    k_count<<<(EE + 255) / 256, 256, 0, stream>>>(dst, deg);
    k_scan1<<<SCAN_G, 256, 0, stream>>>(deg, bsum);
    k_scan2<<<1, 256, 0, stream>>>(bsum, boff, row_ptr);
    k_scan3<<<SCAN_G, 256, 0, stream>>>(deg, boff, row_ptr);
    k_fill<<<(EE + 255) / 256, 256, 0, stream>>>(src, dst, row_ptr, fill, eid, scsr, dcsr);
    k_cast_esum<<<NN, C, 0, stream>>>(ea, eid, row_ptr, ea_u, es_u);

    int gN = (NN + 127) / 128, gE = (EE + 127) / 128;

    // ---- layer 1 ----
    k_gemm2<<<gN, 256, 0, stream>>>(x_u, WTl1, bl1, WTr1, br1, xl_u, xr_u, NN);
    k_gemm_logit<true ><<<gN, 256, 0, stream>>>(es_u, WTe1, xl_u, xr_u, nullptr, nullptr, att1, a + EE, NN);
    k_gemm_logit<false><<<gE, 256, 0, stream>>>(ea_u, WTe1, xl_u, xr_u, scsr, dcsr, att1, a, EE);
    k_attn<<<(NN + 3) / 4, 256, 0, stream>>>(xl_u, a, row_ptr, scsr, bo1, aggf);
    k_bnstats<<<256, 1024, 0, stream>>>(aggf, sums);
    k_bnapply<<<(NN * C / 4 + 255) / 256, 256, 0, stream>>>(aggf, sums, g1, be1, h_u);

    // ---- layer 2 ----
    k_gemm2<<<gN, 256, 0, stream>>>(h_u, WTl2, bl2, WTr2, br2, xl_u, xr_u, NN);
    k_gemm_logit<true ><<<gN, 256, 0, stream>>>(es_u, WTe2, xl_u, xr_u, nullptr, nullptr, att2, a + EE, NN);
    k_gemm_logit<false><<<gE, 256, 0, stream>>>(ea_u, WTe2, xl_u, xr_u, scsr, dcsr, att2, a, EE);
    k_attn<<<(NN + 3) / 4, 256, 0, stream>>>(xl_u, a, row_ptr, scsr, bo2, aggf);
    k_bnstats<<<256, 1024, 0, stream>>>(aggf, sums + 2 * C);
    k_bnapply<<<(NN * C / 4 + 255) / 256, 256, 0, stream>>>(aggf, sums + 2 * C, g2, be2, h_u);

    // ---- pooling + head ----
    k_gemm<true,  true><<<gN, 256, 0, stream>>>(h_u,  WTA1, bg1, xl_u, NN);
    k_gemm<false, true><<<gN, 256, 0, stream>>>(xl_u, WTA2, bg2, xr_u, NN);
    k_bounds<<<(NN + 255) / 256, 256, 0, stream>>>(batch, gs, ge);
    k_poolfinal<<<GG, 1024, 0, stream>>>(xr_u, h_u, gs, ge, Wf, bf, (float*)d_out);
}